// Round 9
// baseline (221.943 us; speedup 1.0000x reference)
//
#include <hip/hip_runtime.h>
#include <hip/hip_bf16.h>

// Attention B=4,N=2048,D=384,H=8,DH=48 — Round 8 (R7 + compile fix):
//  - attn: TQ=64, wave = (query-pair, key-half) split -> grid 1024 (4 blk/CU,
//    16 waves/CU); partial-O merge via LDS union (no-max softmax => pure add)
//  - qkv: stages x directly from fp32 (scalar f16 casts), xh buffer gone
//  - prep: weight transposes only (144 blocks)

typedef _Float16 f16x8 __attribute__((ext_vector_type(8)));
typedef _Float16 f16x4 __attribute__((ext_vector_type(4)));
typedef float    f32x4 __attribute__((ext_vector_type(4)));
typedef float    f32x16 __attribute__((ext_vector_type(16)));

// scale * log2(e) = 48^-0.5 * 1.4426950408889634
#define QSCL 0.20822035963448658f

// ---------------------------------------------------------------------------
// prep: LDS-tiled coalesced weight transposes (Wqkv^T, Wproj^T) -> f16 [n][k]
// ---------------------------------------------------------------------------
__global__ __launch_bounds__(256) void prep(const float* __restrict__ wq,
                                            const float* __restrict__ wp,
                                            _Float16* __restrict__ wqt,
                                            _Float16* __restrict__ wpt)
{
    __shared__ _Float16 t[64][65];
    const int blk = blockIdx.x, tid = threadIdx.x;
    const float* src; _Float16* dst; int Nn, k0, n0;
    if (blk < 108) {            // Wqkv: 6 k-tiles x 18 n-tiles
        src = wq; dst = wqt; Nn = 1152;
        k0 = (blk % 6) * 64; n0 = (blk / 6) * 64;
    } else {                    // Wproj: 6 x 6
        const int b2 = blk - 108;
        src = wp; dst = wpt; Nn = 384;
        k0 = (b2 % 6) * 64; n0 = (b2 / 6) * 64;
    }
    #pragma unroll
    for (int i = 0; i < 16; i++) {
        const int id = tid + i * 256;            // 0..4095
        const int k = id >> 6, n = id & 63;      // coalesced over n
        t[k][n] = (_Float16)src[(size_t)(k0 + k) * Nn + n0 + n];
    }
    __syncthreads();
    #pragma unroll
    for (int i = 0; i < 16; i++) {
        const int id = tid + i * 256;
        const int n = id >> 6, k = id & 63;      // coalesced over k
        dst[(size_t)(n0 + n) * 384 + k0 + k] = t[k][n];
    }
}

// ---------------------------------------------------------------------------
// QKV GEMM: A = x[8192][384] fp32 (cvt at staging), Bt = wqkvt[1152][384] f16.
// 128x64 tile, BK=64, padded LDS, 16x16x32 MFMA, 4 waves, reg-prefetch.
// ---------------------------------------------------------------------------
__global__ __launch_bounds__(256) void qkv_f16(const float* __restrict__ X,
                                               const _Float16* __restrict__ Bt,
                                               _Float16* __restrict__ qh,
                                               _Float16* __restrict__ kh,
                                               _Float16* __restrict__ vt)
{
    __shared__ _Float16 As[128][72];
    __shared__ _Float16 Bs[64][72];
    const int tid = threadIdx.x;
    const int w = tid >> 6, lane = tid & 63, cl = lane & 15, quad = lane >> 4;
    const int bm = blockIdx.x, bn = blockIdx.y;

    f32x4 acc[2][4];
    const f32x4 z4 = {0.f, 0.f, 0.f, 0.f};
    #pragma unroll
    for (int mi = 0; mi < 2; mi++)
        #pragma unroll
        for (int t = 0; t < 4; t++) acc[mi][t] = z4;

    const int ar = tid >> 3, ac = (tid & 7) * 8;
    const float*    Ag = X  + (size_t)(bm * 128 + ar) * 384 + ac;
    const _Float16* Bg = Bt + (size_t)(bn * 64  + ar) * 384 + ac;

    float4 pa0[4], pa1[4];
    f16x8 pb[2];
    #pragma unroll
    for (int j = 0; j < 4; j++) {
        pa0[j] = *(const float4*)(Ag + (size_t)(32 * j) * 384);
        pa1[j] = *(const float4*)(Ag + (size_t)(32 * j) * 384 + 4);
    }
    #pragma unroll
    for (int j = 0; j < 2; j++) pb[j] = *(const f16x8*)(Bg + (size_t)(32 * j) * 384);

    for (int k0 = 0; k0 < 384; k0 += 64) {
        __syncthreads();
        #pragma unroll
        for (int j = 0; j < 4; j++) {
            f16x8 hh;
            hh[0] = (_Float16)pa0[j].x; hh[1] = (_Float16)pa0[j].y;
            hh[2] = (_Float16)pa0[j].z; hh[3] = (_Float16)pa0[j].w;
            hh[4] = (_Float16)pa1[j].x; hh[5] = (_Float16)pa1[j].y;
            hh[6] = (_Float16)pa1[j].z; hh[7] = (_Float16)pa1[j].w;
            *(f16x8*)&As[ar + 32 * j][ac] = hh;
        }
        #pragma unroll
        for (int j = 0; j < 2; j++) *(f16x8*)&Bs[ar + 32 * j][ac] = pb[j];
        __syncthreads();
        if (k0 + 64 < 384) {
            #pragma unroll
            for (int j = 0; j < 4; j++) {
                pa0[j] = *(const float4*)(Ag + (size_t)(32 * j) * 384 + k0 + 64);
                pa1[j] = *(const float4*)(Ag + (size_t)(32 * j) * 384 + k0 + 68);
            }
            #pragma unroll
            for (int j = 0; j < 2; j++)
                pb[j] = *(const f16x8*)(Bg + (size_t)(32 * j) * 384 + k0 + 64);
        }
        #pragma unroll
        for (int kh2 = 0; kh2 < 2; kh2++) {
            f16x8 bf[4];
            #pragma unroll
            for (int t = 0; t < 4; t++)
                bf[t] = *(const f16x8*)&Bs[t * 16 + cl][kh2 * 32 + quad * 8];
            #pragma unroll
            for (int mi = 0; mi < 2; mi++) {
                const f16x8 af = *(const f16x8*)&As[w * 32 + mi * 16 + cl][kh2 * 32 + quad * 8];
                #pragma unroll
                for (int t = 0; t < 4; t++)
                    acc[mi][t] = __builtin_amdgcn_mfma_f32_16x16x32_f16(af, bf[t], acc[mi][t], 0, 0, 0);
            }
        }
    }

    const int s = (bn * 64) / 384;    // uniform per block
    #pragma unroll
    for (int t = 0; t < 4; t++) {
        const int col  = bn * 64 + t * 16 + cl - s * 384;  // 0..383
        const int head = col / 48, d = col - head * 48;
        #pragma unroll
        for (int mi = 0; mi < 2; mi++) {
            #pragma unroll
            for (int r = 0; r < 4; r++) {
                const int row = bm * 128 + w * 32 + mi * 16 + quad * 4 + r;  // b*2048+n
                const int b = row >> 11, n = row & 2047;
                const int bh = b * 8 + head;
                const float v = acc[mi][t][r];
                if (s == 0)
                    qh[(size_t)(bh * 2048 + n) * 48 + d] = (_Float16)(v * QSCL);
                else if (s == 1)
                    kh[(size_t)(bh * 2048 + n) * 48 + d] = (_Float16)v;
                else
                    vt[(size_t)(bh * 48 + d) * 2048 + n] = (_Float16)v;
            }
        }
    }
}

// ---------------------------------------------------------------------------
// Flash attention, 32x32x16 f16 MFMA, no-max softmax.
// Block 256 = 4 waves; 64 queries of one (b,h); 64-key tiles.
// Wave role: pair = w>>1 (query group of 32), half = w&1 (key half of 32).
// Per tile/wave: 3 S-MFMAs + 16 exp2 + 4 PV-MFMAs on its 32q x 32k block
// (wave-private Ps rows/cols -> no extra barriers). Partial O merged once at
// the end via LDS (no-max softmax => merge is addition; l = col 48 ones-row).
// ---------------------------------------------------------------------------
union AttnSmem {
    struct {
        _Float16 Ks[64][56];    // [key][dh]     7168 B
        _Float16 Vts[64][72];   // [dh][key]     9216 B; row 48 ones, 49-63 zero
        _Float16 Ps[64][72];    // [query][key]  9216 B
    } a;
    float mb[2][32][50];        // merge buffer (12.8 KB, overlaps Ks/Vts only)
};

__global__ __launch_bounds__(256) void attn_f16(const _Float16* __restrict__ qh,
                                                const _Float16* __restrict__ kh,
                                                const _Float16* __restrict__ vt,
                                                _Float16* __restrict__ ab)
{
    __shared__ AttnSmem sm;
    const int tid = threadIdx.x;
    const int w = tid >> 6, lane = tid & 63, ln = lane & 31, h = lane >> 5;
    const int pair = w >> 1, half = w & 1;
    const int bh = blockIdx.x, qt = blockIdx.y;

    // one-time: Vts rows 48..63 (48 = ones for l, rest zero)
    for (int i = tid; i < 16 * 72; i += 256) {
        const int r = 48 + i / 72, c = i - (i / 72) * 72;
        sm.a.Vts[r][c] = (r == 48) ? (_Float16)1.0f : (_Float16)0.0f;
    }

    // Q B-frags (3, dh = 16i + 8h + 0..7), query = qt*64 + pair*32 + ln
    f16x8 qf[3];
    {
        const _Float16* qp = qh + (size_t)(bh * 2048 + qt * 64 + pair * 32 + ln) * 48 + 8 * h;
        qf[0] = *(const f16x8*)qp;
        qf[1] = *(const f16x8*)(qp + 16);
        qf[2] = *(const f16x8*)(qp + 32);
    }

    f32x16 o0, o1;
    #pragma unroll
    for (int r = 0; r < 16; r++) { o0[r] = 0.f; o1[r] = 0.f; }

    const _Float16* kbase = kh + (size_t)bh * 2048 * 48;
    const _Float16* vbase = vt + (size_t)bh * 48 * 2048;

    const int kr0 = tid / 6,         kc0 = (tid % 6) * 8;
    const int kid1 = tid + 256;
    const int kr1 = kid1 / 6,        kc1 = (kid1 % 6) * 8;
    const int vr0 = tid >> 3,        vc0 = (tid & 7) * 8;
    const int vr1 = (tid + 256) >> 3;
    const _Float16* ks0 = kbase + (size_t)kr0 * 48 + kc0;
    const _Float16* ks1 = kbase + (size_t)kr1 * 48 + kc1;
    const _Float16* vs0 = vbase + (size_t)vr0 * 2048 + vc0;
    const _Float16* vs1 = vbase + (size_t)vr1 * 2048 + vc0;

    // prefetch tile 0
    f16x8 rk0 = *(const f16x8*)ks0;
    f16x8 rv0 = *(const f16x8*)vs0;
    f16x8 rk1, rv1;
    if (tid < 128) { rk1 = *(const f16x8*)ks1; rv1 = *(const f16x8*)vs1; }

    for (int kt = 0; kt < 2048; kt += 64) {
        __syncthreads();
        *(f16x8*)&sm.a.Ks[kr0][kc0]  = rk0;
        *(f16x8*)&sm.a.Vts[vr0][vc0] = rv0;
        if (tid < 128) {
            *(f16x8*)&sm.a.Ks[kr1][kc1]  = rk1;
            *(f16x8*)&sm.a.Vts[vr1][vc0] = rv1;
        }
        __syncthreads();
        if (kt + 64 < 2048) {
            rk0 = *(const f16x8*)(ks0 + (size_t)(kt + 64) * 48);
            rv0 = *(const f16x8*)(vs0 + kt + 64);
            if (tid < 128) {
                rk1 = *(const f16x8*)(ks1 + (size_t)(kt + 64) * 48);
                rv1 = *(const f16x8*)(vs1 + kt + 64);
            }
        }

        // ---- S^T = K.Q^T on this wave's 32-key half ----
        f32x16 s;
        #pragma unroll
        for (int r = 0; r < 16; r++) s[r] = 0.f;
        #pragma unroll
        for (int i = 0; i < 3; i++) {
            const f16x8 ka = *(const f16x8*)&sm.a.Ks[half * 32 + ln][16 * i + 8 * h];
            s = __builtin_amdgcn_mfma_f32_32x32x16_f16(ka, qf[i], s, 0, 0, 0);
        }

        // ---- P = exp2(S^T) -> Ps[query][key], b64 packed stores ----
        #pragma unroll
        for (int q = 0; q < 4; q++) {
            f16x4 pk;
            pk[0] = (_Float16)exp2f(s[4 * q + 0]);
            pk[1] = (_Float16)exp2f(s[4 * q + 1]);
            pk[2] = (_Float16)exp2f(s[4 * q + 2]);
            pk[3] = (_Float16)exp2f(s[4 * q + 3]);
            *(f16x4*)&sm.a.Ps[pair * 32 + ln][half * 32 + 8 * q + 4 * h] = pk;
        }

        // ---- O += P.V on this wave's key half ----
        #pragma unroll
        for (int i = 0; i < 2; i++) {
            const f16x8 pa = *(const f16x8*)&sm.a.Ps[pair * 32 + ln][half * 32 + 16 * i + 8 * h];
            const f16x8 v0 = *(const f16x8*)&sm.a.Vts[ln][half * 32 + 16 * i + 8 * h];
            o0 = __builtin_amdgcn_mfma_f32_32x32x16_f16(pa, v0, o0, 0, 0, 0);
            const f16x8 v1 = *(const f16x8*)&sm.a.Vts[32 + ln][half * 32 + 16 * i + 8 * h];
            o1 = __builtin_amdgcn_mfma_f32_32x32x16_f16(pa, v1, o1, 0, 0, 0);
        }
    }

    // ---- merge key-halves (pure addition), normalize, store ----
    __syncthreads();                  // all Vts/Ps reads done; mb aliases Ks/Vts
    if (half == 1) {
        #pragma unroll
        for (int r = 0; r < 16; r++) {
            const int row = (r & 3) + 8 * (r >> 2) + 4 * h;
            sm.mb[pair][row][ln] = o0[r];
            if (ln < 17) sm.mb[pair][row][32 + ln] = o1[r];
        }
    }
    __syncthreads();
    if (half == 0) {
        const int b = bh >> 3, hd = bh & 7;
        #pragma unroll
        for (int r = 0; r < 16; r++) {
            const int row = (r & 3) + 8 * (r >> 2) + 4 * h;
            o0[r] += sm.mb[pair][row][ln];
            if (ln < 17) o1[r] += sm.mb[pair][row][32 + ln];
            const float lr = __shfl(o1[r], (lane & 32) + 16);
            const float inv = 1.f / lr;
            const int q = qt * 64 + pair * 32 + row;
            _Float16* orow = ab + (size_t)(b * 2048 + q) * 384 + hd * 48;
            orow[ln] = (_Float16)(o0[r] * inv);
            if (ln < 16) orow[32 + ln] = (_Float16)(o1[r] * inv);
        }
    }
}

// ---------------------------------------------------------------------------
// Proj GEMM: A = ab[8192][384] f16, Bt = wprojt[384][384] f16, +bias -> fp32
// 64x64 tile, BK=64, padded LDS, reg-prefetch.
// ---------------------------------------------------------------------------
__global__ __launch_bounds__(256) void proj_f16(const _Float16* __restrict__ A,
                                                const _Float16* __restrict__ Bt,
                                                const float* __restrict__ bias,
                                                float* __restrict__ out)
{
    __shared__ _Float16 As[64][72];
    __shared__ _Float16 Bs[64][72];
    const int tid = threadIdx.x;
    const int w = tid >> 6, lane = tid & 63, cl = lane & 15, quad = lane >> 4;
    const int bm = blockIdx.x, bn = blockIdx.y;

    f32x4 acc[4];
    const f32x4 z4 = {0.f, 0.f, 0.f, 0.f};
    #pragma unroll
    for (int t = 0; t < 4; t++) acc[t] = z4;

    const int ar = tid >> 3, ac = (tid & 7) * 8;
    const _Float16* Ag = A  + (size_t)(bm * 64 + ar) * 384 + ac;
    const _Float16* Bg = Bt + (size_t)(bn * 64 + ar) * 384 + ac;

    f16x8 pa[2], pb[2];
    #pragma unroll
    for (int j = 0; j < 2; j++) {
        pa[j] = *(const f16x8*)(Ag + (size_t)(32 * j) * 384);
        pb[j] = *(const f16x8*)(Bg + (size_t)(32 * j) * 384);
    }

    for (int k0 = 0; k0 < 384; k0 += 64) {
        __syncthreads();
        #pragma unroll
        for (int j = 0; j < 2; j++) {
            *(f16x8*)&As[ar + 32 * j][ac] = pa[j];
            *(f16x8*)&Bs[ar + 32 * j][ac] = pb[j];
        }
        __syncthreads();
        if (k0 + 64 < 384) {
            #pragma unroll
            for (int j = 0; j < 2; j++) {
                pa[j] = *(const f16x8*)(Ag + (size_t)(32 * j) * 384 + k0 + 64);
                pb[j] = *(const f16x8*)(Bg + (size_t)(32 * j) * 384 + k0 + 64);
            }
        }
        #pragma unroll
        for (int kh2 = 0; kh2 < 2; kh2++) {
            const f16x8 af = *(const f16x8*)&As[w * 16 + cl][kh2 * 32 + quad * 8];
            #pragma unroll
            for (int t = 0; t < 4; t++) {
                const f16x8 bf = *(const f16x8*)&Bs[t * 16 + cl][kh2 * 32 + quad * 8];
                acc[t] = __builtin_amdgcn_mfma_f32_16x16x32_f16(af, bf, acc[t], 0, 0, 0);
            }
        }
    }

    #pragma unroll
    for (int t = 0; t < 4; t++) {
        const int col = bn * 64 + t * 16 + cl;
        const float bv = bias[col];
        #pragma unroll
        for (int r = 0; r < 4; r++) {
            const int row = bm * 64 + w * 16 + quad * 4 + r;
            out[(size_t)row * 384 + col] = acc[t][r] + bv;
        }
    }
}

// ---------------------------------------------------------------------------
extern "C" void kernel_launch(void* const* d_in, const int* in_sizes, int n_in,
                              void* d_out, int out_size, void* d_ws, size_t ws_size,
                              hipStream_t stream) {
    const float* x     = (const float*)d_in[0];  // [4,2048,384]
    const float* Wqkv  = (const float*)d_in[1];  // [384,1152]
    const float* Wproj = (const float*)d_in[2];  // [384,384]
    const float* bproj = (const float*)d_in[3];  // [384]
    float* out = (float*)d_out;

    char* ws = (char*)d_ws;
    _Float16* wqkvt  = (_Float16*)(ws + 0);          // 1152*384*2 =   884,736
    _Float16* wprojt = (_Float16*)(ws + 884736);     // 384*384*2  =   294,912
    _Float16* qh     = (_Float16*)(ws + 1179648);    // 32*2048*48*2 = 6,291,456
    _Float16* kh     = (_Float16*)(ws + 7471104);    // 6,291,456
    _Float16* vt     = (_Float16*)(ws + 13762560);   // 6,291,456
    _Float16* ab     = (_Float16*)(ws + 20054016);   // 6,291,456
    // total 26,345,472 B

    prep<<<144, 256, 0, stream>>>(Wqkv, Wproj, wqkvt, wprojt);
    qkv_f16<<<dim3(64, 18), 256, 0, stream>>>(x, wqkvt, qh, kh, vt);
    attn_f16<<<dim3(32, 32), 256, 0, stream>>>(qh, kh, vt, ab);
    proj_f16<<<dim3(128, 6), 256, 0, stream>>>(ab, wprojt, bproj, out);
}

// Round 10
// 152.376 us; speedup vs baseline: 1.4566x; 1.4566x over previous
//
#include <hip/hip_runtime.h>
#include <hip/hip_bf16.h>

// Attention B=4,N=2048,D=384,H=8,DH=48 — Round 9:
//  - attn: REVERT to R6 structure (TQ=128, 4 full-key waves) — R8 key-split
//    blew up LDS conflicts 15x (cross-wave bank contention at 4 blk/CU)
//  - qkv: V output routed through LDS transpose -> coalesced b128 stores
//    (was 32 scattered 2-byte stores/thread at stride 4KB)

typedef _Float16 f16x8 __attribute__((ext_vector_type(8)));
typedef _Float16 f16x4 __attribute__((ext_vector_type(4)));
typedef float    f32x4 __attribute__((ext_vector_type(4)));
typedef float    f32x16 __attribute__((ext_vector_type(16)));

// scale * log2(e) = 48^-0.5 * 1.4426950408889634
#define QSCL 0.20822035963448658f

// ---------------------------------------------------------------------------
// prep: LDS-tiled coalesced weight transposes (Wqkv^T, Wproj^T) -> f16 [n][k]
// ---------------------------------------------------------------------------
__global__ __launch_bounds__(256) void prep(const float* __restrict__ wq,
                                            const float* __restrict__ wp,
                                            _Float16* __restrict__ wqt,
                                            _Float16* __restrict__ wpt)
{
    __shared__ _Float16 t[64][65];
    const int blk = blockIdx.x, tid = threadIdx.x;
    const float* src; _Float16* dst; int Nn, k0, n0;
    if (blk < 108) {            // Wqkv: 6 k-tiles x 18 n-tiles
        src = wq; dst = wqt; Nn = 1152;
        k0 = (blk % 6) * 64; n0 = (blk / 6) * 64;
    } else {                    // Wproj: 6 x 6
        const int b2 = blk - 108;
        src = wp; dst = wpt; Nn = 384;
        k0 = (b2 % 6) * 64; n0 = (b2 / 6) * 64;
    }
    #pragma unroll
    for (int i = 0; i < 16; i++) {
        const int id = tid + i * 256;            // 0..4095
        const int k = id >> 6, n = id & 63;      // coalesced over n
        t[k][n] = (_Float16)src[(size_t)(k0 + k) * Nn + n0 + n];
    }
    __syncthreads();
    #pragma unroll
    for (int i = 0; i < 16; i++) {
        const int id = tid + i * 256;
        const int n = id >> 6, k = id & 63;      // coalesced over k
        dst[(size_t)(n0 + n) * 384 + k0 + k] = t[k][n];
    }
}

// ---------------------------------------------------------------------------
// QKV GEMM: A = x[8192][384] fp32 (cvt at staging), Bt = wqkvt[1152][384] f16.
// 128x64 tile, BK=64, padded LDS, 16x16x32 MFMA, 4 waves, reg-prefetch.
// s==2 (V) blocks: epilogue via LDS transpose -> coalesced b128 stores.
// ---------------------------------------------------------------------------
union QkvSmem {
    struct { _Float16 As[128][72]; _Float16 Bs[64][72]; } g;  // 27648 B
    _Float16 Ts[64][136];   // transpose buffer [col][n] 17408 B (aliases As)
};

__global__ __launch_bounds__(256) void qkv_f16(const float* __restrict__ X,
                                               const _Float16* __restrict__ Bt,
                                               _Float16* __restrict__ qh,
                                               _Float16* __restrict__ kh,
                                               _Float16* __restrict__ vt)
{
    __shared__ QkvSmem sm;
    const int tid = threadIdx.x;
    const int w = tid >> 6, lane = tid & 63, cl = lane & 15, quad = lane >> 4;
    const int bm = blockIdx.x, bn = blockIdx.y;

    f32x4 acc[2][4];
    const f32x4 z4 = {0.f, 0.f, 0.f, 0.f};
    #pragma unroll
    for (int mi = 0; mi < 2; mi++)
        #pragma unroll
        for (int t = 0; t < 4; t++) acc[mi][t] = z4;

    const int ar = tid >> 3, ac = (tid & 7) * 8;
    const float*    Ag = X  + (size_t)(bm * 128 + ar) * 384 + ac;
    const _Float16* Bg = Bt + (size_t)(bn * 64  + ar) * 384 + ac;

    float4 pa0[4], pa1[4];
    f16x8 pb[2];
    #pragma unroll
    for (int j = 0; j < 4; j++) {
        pa0[j] = *(const float4*)(Ag + (size_t)(32 * j) * 384);
        pa1[j] = *(const float4*)(Ag + (size_t)(32 * j) * 384 + 4);
    }
    #pragma unroll
    for (int j = 0; j < 2; j++) pb[j] = *(const f16x8*)(Bg + (size_t)(32 * j) * 384);

    for (int k0 = 0; k0 < 384; k0 += 64) {
        __syncthreads();
        #pragma unroll
        for (int j = 0; j < 4; j++) {
            f16x8 hh;
            hh[0] = (_Float16)pa0[j].x; hh[1] = (_Float16)pa0[j].y;
            hh[2] = (_Float16)pa0[j].z; hh[3] = (_Float16)pa0[j].w;
            hh[4] = (_Float16)pa1[j].x; hh[5] = (_Float16)pa1[j].y;
            hh[6] = (_Float16)pa1[j].z; hh[7] = (_Float16)pa1[j].w;
            *(f16x8*)&sm.g.As[ar + 32 * j][ac] = hh;
        }
        #pragma unroll
        for (int j = 0; j < 2; j++) *(f16x8*)&sm.g.Bs[ar + 32 * j][ac] = pb[j];
        __syncthreads();
        if (k0 + 64 < 384) {
            #pragma unroll
            for (int j = 0; j < 4; j++) {
                pa0[j] = *(const float4*)(Ag + (size_t)(32 * j) * 384 + k0 + 64);
                pa1[j] = *(const float4*)(Ag + (size_t)(32 * j) * 384 + k0 + 68);
            }
            #pragma unroll
            for (int j = 0; j < 2; j++)
                pb[j] = *(const f16x8*)(Bg + (size_t)(32 * j) * 384 + k0 + 64);
        }
        #pragma unroll
        for (int kh2 = 0; kh2 < 2; kh2++) {
            f16x8 bf[4];
            #pragma unroll
            for (int t = 0; t < 4; t++)
                bf[t] = *(const f16x8*)&sm.g.Bs[t * 16 + cl][kh2 * 32 + quad * 8];
            #pragma unroll
            for (int mi = 0; mi < 2; mi++) {
                const f16x8 af = *(const f16x8*)&sm.g.As[w * 32 + mi * 16 + cl][kh2 * 32 + quad * 8];
                #pragma unroll
                for (int t = 0; t < 4; t++)
                    acc[mi][t] = __builtin_amdgcn_mfma_f32_16x16x32_f16(af, bf[t], acc[mi][t], 0, 0, 0);
            }
        }
    }

    const int s = (bn * 64) / 384;    // uniform per block
    if (s == 2) {
        // ---- V: LDS transpose -> coalesced stores along n ----
        __syncthreads();              // all fragment reads done
        #pragma unroll
        for (int t = 0; t < 4; t++)
            #pragma unroll
            for (int mi = 0; mi < 2; mi++)
                #pragma unroll
                for (int r = 0; r < 4; r++)
                    sm.Ts[t * 16 + cl][w * 32 + mi * 16 + quad * 4 + r] =
                        (_Float16)acc[mi][t][r];
        __syncthreads();
        const int colbase = bn * 64 - 768;       // 0..320
        const int b  = (bm * 128) >> 11;         // constant per block
        const int n0 = (bm * 128) & 2047;
        #pragma unroll
        for (int i = 0; i < 4; i++) {
            const int c = i * 256 + tid;         // 0..1023 chunks of 8
            const int col = c >> 4, nc = c & 15;
            const int gcol = colbase + col;
            const int head = gcol / 48, d = gcol - head * 48;
            const int bh = b * 8 + head;
            *(f16x8*)&vt[(size_t)(bh * 48 + d) * 2048 + n0 + nc * 8] =
                *(const f16x8*)&sm.Ts[col][nc * 8];
        }
    } else {
        #pragma unroll
        for (int t = 0; t < 4; t++) {
            const int col  = bn * 64 + t * 16 + cl - s * 384;  // 0..383
            const int head = col / 48, d = col - head * 48;
            #pragma unroll
            for (int mi = 0; mi < 2; mi++) {
                #pragma unroll
                for (int r = 0; r < 4; r++) {
                    const int row = bm * 128 + w * 32 + mi * 16 + quad * 4 + r;
                    const int b = row >> 11, n = row & 2047;
                    const int bh = b * 8 + head;
                    const float v = acc[mi][t][r];
                    if (s == 0)
                        qh[(size_t)(bh * 2048 + n) * 48 + d] = (_Float16)(v * QSCL);
                    else
                        kh[(size_t)(bh * 2048 + n) * 48 + d] = (_Float16)v;
                }
            }
        }
    }
}

// ---------------------------------------------------------------------------
// Flash attention, 32x32x16 f16 MFMA, no-max softmax, reg-prefetch staging.
// Block 256 = 4 waves; 128 queries of one (b,h); 64-key tiles. (R6 version)
// ---------------------------------------------------------------------------
__global__ __launch_bounds__(256) void attn_f16(const _Float16* __restrict__ qh,
                                                const _Float16* __restrict__ kh,
                                                const _Float16* __restrict__ vt,
                                                _Float16* __restrict__ ab)
{
    __shared__ _Float16 Ks[64][56];    // [key][dh]    7 KB
    __shared__ _Float16 Vts[64][72];   // [dh][key]    9 KB; row 48 ones, 49-63 zero
    __shared__ _Float16 Ps[128][72];   // [query][key] 18 KB
    const int tid = threadIdx.x;
    const int w = tid >> 6, lane = tid & 63, ln = lane & 31, h = lane >> 5;
    const int bh = blockIdx.x, qt = blockIdx.y;

    // one-time: Vts rows 48..63 (48 = ones for l, rest zero)
    for (int i = tid; i < 16 * 72; i += 256) {
        const int r = 48 + i / 72, c = i - (i / 72) * 72;
        Vts[r][c] = (r == 48) ? (_Float16)1.0f : (_Float16)0.0f;
    }

    // Q B-frags (3, dh = 16i + 8h + 0..7), query = qt*128 + w*32 + ln
    f16x8 qf[3];
    {
        const _Float16* qp = qh + (size_t)(bh * 2048 + qt * 128 + w * 32 + ln) * 48 + 8 * h;
        qf[0] = *(const f16x8*)qp;
        qf[1] = *(const f16x8*)(qp + 16);
        qf[2] = *(const f16x8*)(qp + 32);
    }

    f32x16 o0, o1;
    #pragma unroll
    for (int r = 0; r < 16; r++) { o0[r] = 0.f; o1[r] = 0.f; }

    const _Float16* kbase = kh + (size_t)bh * 2048 * 48;
    const _Float16* vbase = vt + (size_t)bh * 48 * 2048;

    const int kr0 = tid / 6,         kc0 = (tid % 6) * 8;
    const int kid1 = tid + 256;
    const int kr1 = kid1 / 6,        kc1 = (kid1 % 6) * 8;
    const int vr0 = tid >> 3,        vc0 = (tid & 7) * 8;
    const int vr1 = (tid + 256) >> 3;
    const _Float16* ks0 = kbase + (size_t)kr0 * 48 + kc0;
    const _Float16* ks1 = kbase + (size_t)kr1 * 48 + kc1;
    const _Float16* vs0 = vbase + (size_t)vr0 * 2048 + vc0;
    const _Float16* vs1 = vbase + (size_t)vr1 * 2048 + vc0;

    // prefetch tile 0 into registers
    f16x8 rk0 = *(const f16x8*)ks0;
    f16x8 rv0 = *(const f16x8*)vs0;
    f16x8 rk1, rv1;
    if (tid < 128) { rk1 = *(const f16x8*)ks1; rv1 = *(const f16x8*)vs1; }

    for (int kt = 0; kt < 2048; kt += 64) {
        __syncthreads();
        *(f16x8*)&Ks[kr0][kc0]  = rk0;
        *(f16x8*)&Vts[vr0][vc0] = rv0;
        if (tid < 128) {
            *(f16x8*)&Ks[kr1][kc1]  = rk1;
            *(f16x8*)&Vts[vr1][vc0] = rv1;
        }
        __syncthreads();
        if (kt + 64 < 2048) {        // issue next-tile loads; waited at next write
            rk0 = *(const f16x8*)(ks0 + (size_t)(kt + 64) * 48);
            rv0 = *(const f16x8*)(vs0 + kt + 64);
            if (tid < 128) {
                rk1 = *(const f16x8*)(ks1 + (size_t)(kt + 64) * 48);
                rv1 = *(const f16x8*)(vs1 + kt + 64);
            }
        }

        // ---- S^T = K.Q^T : per key-group, C[key 32][query 32] ----
        f32x16 s0, s1;
        #pragma unroll
        for (int r = 0; r < 16; r++) { s0[r] = 0.f; s1[r] = 0.f; }
        #pragma unroll
        for (int i = 0; i < 3; i++) {
            const f16x8 ka0 = *(const f16x8*)&Ks[ln][16 * i + 8 * h];
            s0 = __builtin_amdgcn_mfma_f32_32x32x16_f16(ka0, qf[i], s0, 0, 0, 0);
            const f16x8 ka1 = *(const f16x8*)&Ks[32 + ln][16 * i + 8 * h];
            s1 = __builtin_amdgcn_mfma_f32_32x32x16_f16(ka1, qf[i], s1, 0, 0, 0);
        }

        // ---- P = exp2(S^T) -> Ps[query][key], b64 packed stores ----
        #pragma unroll
        for (int q = 0; q < 4; q++) {
            f16x4 pk;
            pk[0] = (_Float16)exp2f(s0[4 * q + 0]);
            pk[1] = (_Float16)exp2f(s0[4 * q + 1]);
            pk[2] = (_Float16)exp2f(s0[4 * q + 2]);
            pk[3] = (_Float16)exp2f(s0[4 * q + 3]);
            *(f16x4*)&Ps[w * 32 + ln][8 * q + 4 * h] = pk;
            f16x4 pk1;
            pk1[0] = (_Float16)exp2f(s1[4 * q + 0]);
            pk1[1] = (_Float16)exp2f(s1[4 * q + 1]);
            pk1[2] = (_Float16)exp2f(s1[4 * q + 2]);
            pk1[3] = (_Float16)exp2f(s1[4 * q + 3]);
            *(f16x4*)&Ps[w * 32 + ln][32 + 8 * q + 4 * h] = pk1;
        }

        // ---- O += P.V : A=Ps rows (wave-private), B=Vts ----
        #pragma unroll
        for (int i = 0; i < 4; i++) {
            const f16x8 pa = *(const f16x8*)&Ps[w * 32 + ln][16 * i + 8 * h];
            const f16x8 v0 = *(const f16x8*)&Vts[ln][16 * i + 8 * h];
            o0 = __builtin_amdgcn_mfma_f32_32x32x16_f16(pa, v0, o0, 0, 0, 0);
            const f16x8 v1 = *(const f16x8*)&Vts[32 + ln][16 * i + 8 * h];
            o1 = __builtin_amdgcn_mfma_f32_32x32x16_f16(pa, v1, o1, 0, 0, 0);
        }
    }

    // ---- normalize + store. l = O col 48 = cg1 col 16 -> lane h*32+16 ----
    const int b = bh >> 3, hd = bh & 7;
    #pragma unroll
    for (int r = 0; r < 16; r++) {
        const float lr = __shfl(o1[r], (lane & 32) + 16);
        const float inv = 1.f / lr;
        const int q = qt * 128 + w * 32 + (r & 3) + 8 * (r >> 2) + 4 * h;
        _Float16* orow = ab + (size_t)(b * 2048 + q) * 384 + hd * 48;
        orow[ln] = (_Float16)(o0[r] * inv);
        if (ln < 16) orow[32 + ln] = (_Float16)(o1[r] * inv);
    }
}

// ---------------------------------------------------------------------------
// Proj GEMM: A = ab[8192][384] f16, Bt = wprojt[384][384] f16, +bias -> fp32
// 64x64 tile, BK=64, padded LDS, reg-prefetch.
// ---------------------------------------------------------------------------
__global__ __launch_bounds__(256) void proj_f16(const _Float16* __restrict__ A,
                                                const _Float16* __restrict__ Bt,
                                                const float* __restrict__ bias,
                                                float* __restrict__ out)
{
    __shared__ _Float16 As[64][72];
    __shared__ _Float16 Bs[64][72];
    const int tid = threadIdx.x;
    const int w = tid >> 6, lane = tid & 63, cl = lane & 15, quad = lane >> 4;
    const int bm = blockIdx.x, bn = blockIdx.y;

    f32x4 acc[4];
    const f32x4 z4 = {0.f, 0.f, 0.f, 0.f};
    #pragma unroll
    for (int t = 0; t < 4; t++) acc[t] = z4;

    const int ar = tid >> 3, ac = (tid & 7) * 8;
    const _Float16* Ag = A  + (size_t)(bm * 64 + ar) * 384 + ac;
    const _Float16* Bg = Bt + (size_t)(bn * 64 + ar) * 384 + ac;

    f16x8 pa[2], pb[2];
    #pragma unroll
    for (int j = 0; j < 2; j++) {
        pa[j] = *(const f16x8*)(Ag + (size_t)(32 * j) * 384);
        pb[j] = *(const f16x8*)(Bg + (size_t)(32 * j) * 384);
    }

    for (int k0 = 0; k0 < 384; k0 += 64) {
        __syncthreads();
        #pragma unroll
        for (int j = 0; j < 2; j++) {
            *(f16x8*)&As[ar + 32 * j][ac] = pa[j];
            *(f16x8*)&Bs[ar + 32 * j][ac] = pb[j];
        }
        __syncthreads();
        if (k0 + 64 < 384) {
            #pragma unroll
            for (int j = 0; j < 2; j++) {
                pa[j] = *(const f16x8*)(Ag + (size_t)(32 * j) * 384 + k0 + 64);
                pb[j] = *(const f16x8*)(Bg + (size_t)(32 * j) * 384 + k0 + 64);
            }
        }
        #pragma unroll
        for (int kh2 = 0; kh2 < 2; kh2++) {
            const f16x8 af = *(const f16x8*)&As[w * 16 + cl][kh2 * 32 + quad * 8];
            #pragma unroll
            for (int t = 0; t < 4; t++) {
                const f16x8 bf = *(const f16x8*)&Bs[t * 16 + cl][kh2 * 32 + quad * 8];
                acc[t] = __builtin_amdgcn_mfma_f32_16x16x32_f16(af, bf, acc[t], 0, 0, 0);
            }
        }
    }

    #pragma unroll
    for (int t = 0; t < 4; t++) {
        const int col = bn * 64 + t * 16 + cl;
        const float bv = bias[col];
        #pragma unroll
        for (int r = 0; r < 4; r++) {
            const int row = bm * 64 + w * 16 + quad * 4 + r;
            out[(size_t)row * 384 + col] = acc[t][r] + bv;
        }
    }
}

// ---------------------------------------------------------------------------
extern "C" void kernel_launch(void* const* d_in, const int* in_sizes, int n_in,
                              void* d_out, int out_size, void* d_ws, size_t ws_size,
                              hipStream_t stream) {
    const float* x     = (const float*)d_in[0];  // [4,2048,384]
    const float* Wqkv  = (const float*)d_in[1];  // [384,1152]
    const float* Wproj = (const float*)d_in[2];  // [384,384]
    const float* bproj = (const float*)d_in[3];  // [384]
    float* out = (float*)d_out;

    char* ws = (char*)d_ws;
    _Float16* wqkvt  = (_Float16*)(ws + 0);          // 1152*384*2 =   884,736
    _Float16* wprojt = (_Float16*)(ws + 884736);     // 384*384*2  =   294,912
    _Float16* qh     = (_Float16*)(ws + 1179648);    // 32*2048*48*2 = 6,291,456
    _Float16* kh     = (_Float16*)(ws + 7471104);    // 6,291,456
    _Float16* vt     = (_Float16*)(ws + 13762560);   // 6,291,456
    _Float16* ab     = (_Float16*)(ws + 20054016);   // 6,291,456
    // total 26,345,472 B

    prep<<<144, 256, 0, stream>>>(Wqkv, Wproj, wqkvt, wprojt);
    qkv_f16<<<dim3(64, 18), 256, 0, stream>>>(x, wqkvt, qh, kh, vt);
    attn_f16<<<dim3(32, 16), 256, 0, stream>>>(qh, kh, vt, ab);
    proj_f16<<<dim3(128, 6), 256, 0, stream>>>(ab, wprojt, bproj, out);
}